// Round 1
// baseline (278.044 us; speedup 1.0000x reference)
//
#include <hip/hip_runtime.h>
#include <hip/hip_bf16.h>

typedef unsigned short u16;
typedef __attribute__((ext_vector_type(8))) short bf16x8;
typedef __attribute__((ext_vector_type(4))) float f32x4;
typedef __attribute__((ext_vector_type(8))) unsigned short u16x8;

#define BATCH 4096
#define INF   1024
#define NH    4096   // 64 leaves * 64 hidden
#define OUTF  512
#define NLEAF 64
#define FDEPTH 6

// Scratch as device globals (fully rewritten every call; no ws_size dependency).
__device__ __align__(16) u16  g_Xb[(size_t)BATCH * INF];    // x, bf16 (b,k)
__device__ __align__(16) u16  g_W1t[(size_t)NH * INF];      // W1 transposed: (n, k)
__device__ __align__(16) u16  g_W2t[(size_t)OUTF * NH];     // W2 transposed: (o, k)
__device__ __align__(16) u16  g_Hb[(size_t)BATCH * NH];     // H' = mix*relu(h), bf16 (b, n)
__device__ __align__(16) float g_mix[(size_t)BATCH * NLEAF];

__device__ inline u16 f2b(float f) {
  __hip_bfloat16 h = __float2bfloat16(f);
  return *reinterpret_cast<u16*>(&h);
}

// ---------------- cast x -> bf16 ----------------
__global__ __launch_bounds__(256) void cast_x_kernel(const float* __restrict__ x) {
  int i = (blockIdx.x * 256 + threadIdx.x) * 8;
  float4 v0 = *(const float4*)(x + i);
  float4 v1 = *(const float4*)(x + i + 4);
  u16x8 o;
  o[0] = f2b(v0.x); o[1] = f2b(v0.y); o[2] = f2b(v0.z); o[3] = f2b(v0.w);
  o[4] = f2b(v1.x); o[5] = f2b(v1.y); o[6] = f2b(v1.z); o[7] = f2b(v1.w);
  *(u16x8*)(g_Xb + i) = o;
}

// ------------- batched transpose + cast: dst[b][c][r] = src[b][r][c] -------------
// which==0 -> g_W1t (batch=64, R=1024, C=64); which==1 -> g_W2t (batch=1, R=4096, C=512)
__global__ __launch_bounds__(256) void transpose_cast_kernel(const float* __restrict__ src,
                                                             int which, int R, int C) {
  __shared__ float tile[64 * 65];
  u16* dstbase = which ? g_W2t : g_W1t;
  const float* sb = src + (size_t)blockIdx.z * R * C;
  u16* db = dstbase + (size_t)blockIdx.z * R * C;
  int r0 = blockIdx.y * 64, c0 = blockIdx.x * 64;
  int t = threadIdx.x;
  int cc4 = (t & 15) * 4;
#pragma unroll
  for (int it = 0; it < 4; ++it) {
    int rr = (t >> 4) + it * 16;
    float4 v = *(const float4*)(sb + (size_t)(r0 + rr) * C + c0 + cc4);
    tile[rr * 65 + cc4 + 0] = v.x;
    tile[rr * 65 + cc4 + 1] = v.y;
    tile[rr * 65 + cc4 + 2] = v.z;
    tile[rr * 65 + cc4 + 3] = v.w;
  }
  __syncthreads();
  int cc = t >> 2, rch = (t & 3) * 16;
  u16x8 o0, o1;
#pragma unroll
  for (int j = 0; j < 8; ++j) o0[j] = f2b(tile[(rch + j) * 65 + cc]);
#pragma unroll
  for (int j = 0; j < 8; ++j) o1[j] = f2b(tile[(rch + 8 + j) * 65 + cc]);
  u16* p = db + (size_t)(c0 + cc) * R + r0 + rch;
  *(u16x8*)p = o0;
  *(u16x8*)(p + 8) = o1;
}

// ------------- mixture (fp32) + out := mix @ b2s -------------
__global__ __launch_bounds__(256) void mixture_bias_kernel(
    const float* __restrict__ x, const float* __restrict__ nw,
    const float* __restrict__ nb, const float* __restrict__ b2,
    float* __restrict__ out) {
  __shared__ float xs[4][1024];
  __shared__ float sig[4][64];
  __shared__ float smix[4][64];
  const int t = threadIdx.x;
  const int b0 = blockIdx.x * 4;
  const int wv = t >> 6, l64 = t & 63;
#pragma unroll
  for (int c = 0; c < 4; ++c) {
    int i = l64 * 4 + c * 256;
    *(float4*)&xs[wv][i] = *(const float4*)(x + (size_t)(b0 + wv) * 1024 + i);
  }
  __syncthreads();
  // each wave handles nodes wv, wv+4, ...
  for (int n = wv; n < 63; n += 4) {
    float a0 = 0.f, a1 = 0.f, a2 = 0.f, a3 = 0.f;
#pragma unroll
    for (int c = 0; c < 4; ++c) {
      int i = l64 * 4 + c * 256;
      float4 w = *(const float4*)(nw + (size_t)n * 1024 + i);
      float4 x0 = *(const float4*)&xs[0][i];
      float4 x1 = *(const float4*)&xs[1][i];
      float4 x2 = *(const float4*)&xs[2][i];
      float4 x3 = *(const float4*)&xs[3][i];
      a0 += w.x * x0.x + w.y * x0.y + w.z * x0.z + w.w * x0.w;
      a1 += w.x * x1.x + w.y * x1.y + w.z * x1.z + w.w * x1.w;
      a2 += w.x * x2.x + w.y * x2.y + w.z * x2.z + w.w * x2.w;
      a3 += w.x * x3.x + w.y * x3.y + w.z * x3.z + w.w * x3.w;
    }
#pragma unroll
    for (int off = 32; off > 0; off >>= 1) {
      a0 += __shfl_down(a0, off);
      a1 += __shfl_down(a1, off);
      a2 += __shfl_down(a2, off);
      a3 += __shfl_down(a3, off);
    }
    if (l64 == 0) {
      float bias = nb[n];
      sig[0][n] = 1.f / (1.f + __expf(-(a0 + bias)));
      sig[1][n] = 1.f / (1.f + __expf(-(a1 + bias)));
      sig[2][n] = 1.f / (1.f + __expf(-(a2 + bias)));
      sig[3][n] = 1.f / (1.f + __expf(-(a3 + bias)));
    }
  }
  __syncthreads();
  {
    float p = 1.f;
#pragma unroll
    for (int d = 0; d < FDEPTH; ++d) {
      int node = (1 << d) - 1 + (l64 >> (FDEPTH - d));
      int bit = (l64 >> (FDEPTH - 1 - d)) & 1;
      float s = sig[wv][node];
      p *= bit ? s : (1.f - s);
    }
    smix[wv][l64] = p;
    g_mix[(size_t)(b0 + wv) * 64 + l64] = p;
  }
  __syncthreads();
#pragma unroll
  for (int c = 0; c < 2; ++c) {
    int o = t + c * 256;
    float acc0 = 0.f, acc1 = 0.f, acc2 = 0.f, acc3 = 0.f;
    for (int l = 0; l < 64; ++l) {
      float bv = b2[(size_t)l * 512 + o];
      acc0 += smix[0][l] * bv;
      acc1 += smix[1][l] * bv;
      acc2 += smix[2][l] * bv;
      acc3 += smix[3][l] * bv;
    }
    out[(size_t)(b0 + 0) * 512 + o] = acc0;
    out[(size_t)(b0 + 1) * 512 + o] = acc1;
    out[(size_t)(b0 + 2) * 512 + o] = acc2;
    out[(size_t)(b0 + 3) * 512 + o] = acc3;
  }
}

// ------------- MFMA GEMM (MODE 1: X@W1t -> H'; MODE 2: H'@W2t -> +=out) -------------
template <int MODE>
__global__ __launch_bounds__(256) void gemm_kernel(const float* __restrict__ b1,
                                                   float* __restrict__ out) {
  constexpr int BM = (MODE == 1) ? 128 : 64;
  constexpr int BN = 128;
  constexpr int K = (MODE == 1) ? 1024 : 4096;
  constexpr int LDA = (MODE == 1) ? 1024 : 4096;
  constexpr int LDB = (MODE == 1) ? 1024 : 4096;
  constexpr int LDC = (MODE == 1) ? 4096 : 512;
  constexpr int KSPLIT = (MODE == 1) ? 1 : 2;
  constexpr int BK = 64;
  constexpr int WM = BM / 2, WN = BN / 2;
  constexpr int TM = WM / 16, TN = WN / 16;
  constexpr int LST = BK + 8;  // 72 u16 stride: 16B-aligned, 2-way-bank-free

  const u16* __restrict__ A = (MODE == 1) ? g_Xb : g_Hb;
  const u16* __restrict__ Bm = (MODE == 1) ? g_W1t : g_W2t;

  __shared__ u16 lsA[BM * LST];
  __shared__ u16 lsB[BN * LST];

  const int t = threadIdx.x;
  const int wave = t >> 6, lane = t & 63;
  const int wm = wave >> 1, wn = wave & 1;
  const int quad = lane >> 4, m16 = lane & 15;
  const int am0 = blockIdx.y * BM;
  const int bn0 = blockIdx.x * BN;

  f32x4 acc[TM][TN] = {};

  constexpr int nchA = BM / 32;  // (BM*BK)/(256*8)
  constexpr int nchB = BN / 32;

  const int kbeg = blockIdx.z * (K / KSPLIT);
  const int kend = kbeg + K / KSPLIT;

  for (int kc = kbeg; kc < kend; kc += BK) {
#pragma unroll
    for (int i = 0; i < nchA; ++i) {
      int id = t + 256 * i;
      int row = id >> 3, c8 = id & 7;
      uint4 v = *(const uint4*)(A + (size_t)(am0 + row) * LDA + kc + c8 * 8);
      *(uint4*)(lsA + row * LST + c8 * 8) = v;
    }
#pragma unroll
    for (int i = 0; i < nchB; ++i) {
      int id = t + 256 * i;
      int row = id >> 3, c8 = id & 7;
      uint4 v = *(const uint4*)(Bm + (size_t)(bn0 + row) * LDB + kc + c8 * 8);
      *(uint4*)(lsB + row * LST + c8 * 8) = v;
    }
    __syncthreads();
#pragma unroll
    for (int ks = 0; ks < 2; ++ks) {
      bf16x8 aF[TM], bF[TN];
#pragma unroll
      for (int tm = 0; tm < TM; ++tm)
        aF[tm] = *(const bf16x8*)(lsA + (wm * WM + tm * 16 + m16) * LST + ks * 32 + quad * 8);
#pragma unroll
      for (int tn = 0; tn < TN; ++tn)
        bF[tn] = *(const bf16x8*)(lsB + (wn * WN + tn * 16 + m16) * LST + ks * 32 + quad * 8);
#pragma unroll
      for (int tm = 0; tm < TM; ++tm)
#pragma unroll
        for (int tn = 0; tn < TN; ++tn)
          acc[tm][tn] = __builtin_amdgcn_mfma_f32_16x16x32_bf16(aF[tm], bF[tn], acc[tm][tn], 0, 0, 0);
    }
    __syncthreads();
  }

  if (MODE == 1) {
    float b1v[TN];
    int ls[TN];
#pragma unroll
    for (int tn = 0; tn < TN; ++tn) {
      int col = bn0 + wn * WN + tn * 16 + m16;
      b1v[tn] = b1[col];
      ls[tn] = col >> 6;
    }
#pragma unroll
    for (int tm = 0; tm < TM; ++tm) {
#pragma unroll
      for (int r = 0; r < 4; ++r) {
        int row = am0 + wm * WM + tm * 16 + quad * 4 + r;
        const float* mrow = g_mix + (size_t)row * 64;
#pragma unroll
        for (int tn = 0; tn < TN; ++tn) {
          int col = bn0 + wn * WN + tn * 16 + m16;
          float v = acc[tm][tn][r] + b1v[tn];
          v = fmaxf(v, 0.f) * mrow[ls[tn]];
          g_Hb[(size_t)row * LDC + col] = f2b(v);
        }
      }
    }
  } else {
#pragma unroll
    for (int tm = 0; tm < TM; ++tm)
#pragma unroll
      for (int r = 0; r < 4; ++r) {
        int row = am0 + wm * WM + tm * 16 + quad * 4 + r;
#pragma unroll
        for (int tn = 0; tn < TN; ++tn) {
          int col = bn0 + wn * WN + tn * 16 + m16;
          atomicAdd(&out[(size_t)row * LDC + col], acc[tm][tn][r]);
        }
      }
  }
}

extern "C" void kernel_launch(void* const* d_in, const int* in_sizes, int n_in,
                              void* d_out, int out_size, void* d_ws, size_t ws_size,
                              hipStream_t stream) {
  const float* x = (const float*)d_in[0];
  const float* nw = (const float*)d_in[1];
  const float* nb = (const float*)d_in[2];
  const float* w1s = (const float*)d_in[3];
  const float* b1s = (const float*)d_in[4];
  const float* w2s = (const float*)d_in[5];
  const float* b2s = (const float*)d_in[6];
  float* out = (float*)d_out;

  hipLaunchKernelGGL(cast_x_kernel, dim3(2048), dim3(256), 0, stream, x);
  hipLaunchKernelGGL(transpose_cast_kernel, dim3(1, 16, 64), dim3(256), 0, stream,
                     w1s, 0, 1024, 64);
  hipLaunchKernelGGL(transpose_cast_kernel, dim3(8, 64, 1), dim3(256), 0, stream,
                     w2s, 1, 4096, 512);
  hipLaunchKernelGGL(mixture_bias_kernel, dim3(1024), dim3(256), 0, stream,
                     x, nw, nb, b2s, out);
  hipLaunchKernelGGL(gemm_kernel<1>, dim3(32, 32, 1), dim3(256), 0, stream, b1s, out);
  hipLaunchKernelGGL(gemm_kernel<2>, dim3(4, 64, 2), dim3(256), 0, stream, b1s, out);
}

// Round 2
// 249.429 us; speedup vs baseline: 1.1147x; 1.1147x over previous
//
#include <hip/hip_runtime.h>
#include <hip/hip_bf16.h>

typedef unsigned short u16;
typedef __attribute__((ext_vector_type(8))) short bf16x8;
typedef __attribute__((ext_vector_type(4))) float f32x4;
typedef __attribute__((ext_vector_type(8))) unsigned short u16x8;

#define BATCH 4096
#define INF   1024
#define NH    4096   // 64 leaves * 64 hidden
#define OUTF  512
#define NLEAF 64
#define FDEPTH 6

// Scratch as device globals (fully rewritten every call; no ws_size dependency).
__device__ __align__(16) u16  g_Xb[(size_t)BATCH * INF];    // x, bf16 (b,k)
__device__ __align__(16) u16  g_W1t[(size_t)NH * INF];      // W1 transposed: (n, k)
__device__ __align__(16) u16  g_W2t[(size_t)OUTF * NH];     // W2 transposed: (o, k)
__device__ __align__(16) u16  g_Hb[(size_t)BATCH * NH];     // H' = mix*relu(h), bf16 (b, n)
__device__ __align__(16) float g_mix[(size_t)BATCH * NLEAF];

__device__ inline u16 f2b(float f) {
  __hip_bfloat16 h = __float2bfloat16(f);
  return *reinterpret_cast<u16*>(&h);
}

// Direct global->LDS DMA, 16 B per lane. lds ptr must be wave-uniform; lane i's
// data lands at lptr + i*16.
__device__ inline void async16(const u16* g, u16* l) {
  __builtin_amdgcn_global_load_lds((const __attribute__((address_space(1))) void*)g,
                                   (__attribute__((address_space(3))) void*)l, 16, 0, 0);
}

// ------------- batched transpose + cast: dst[b][c][r] = src[b][r][c] -------------
// which==0 -> g_W1t (batch=64, R=1024, C=64); which==1 -> g_W2t (batch=1, R=4096, C=512)
__global__ __launch_bounds__(256) void transpose_cast_kernel(const float* __restrict__ src,
                                                             int which, int R, int C) {
  __shared__ float tile[64 * 65];
  u16* dstbase = which ? g_W2t : g_W1t;
  const float* sb = src + (size_t)blockIdx.z * R * C;
  u16* db = dstbase + (size_t)blockIdx.z * R * C;
  int r0 = blockIdx.y * 64, c0 = blockIdx.x * 64;
  int t = threadIdx.x;
  int cc4 = (t & 15) * 4;
#pragma unroll
  for (int it = 0; it < 4; ++it) {
    int rr = (t >> 4) + it * 16;
    float4 v = *(const float4*)(sb + (size_t)(r0 + rr) * C + c0 + cc4);
    tile[rr * 65 + cc4 + 0] = v.x;
    tile[rr * 65 + cc4 + 1] = v.y;
    tile[rr * 65 + cc4 + 2] = v.z;
    tile[rr * 65 + cc4 + 3] = v.w;
  }
  __syncthreads();
  int cc = t >> 2, rch = (t & 3) * 16;
  u16x8 o0, o1;
#pragma unroll
  for (int j = 0; j < 8; ++j) o0[j] = f2b(tile[(rch + j) * 65 + cc]);
#pragma unroll
  for (int j = 0; j < 8; ++j) o1[j] = f2b(tile[(rch + 8 + j) * 65 + cc]);
  u16* p = db + (size_t)(c0 + cc) * R + r0 + rch;
  *(u16x8*)p = o0;
  *(u16x8*)(p + 8) = o1;
}

// ------------- mixture (fp32) + out := mix @ b2s + x -> bf16 cast -------------
__global__ __launch_bounds__(256) void mixture_bias_kernel(
    const float* __restrict__ x, const float* __restrict__ nw,
    const float* __restrict__ nb, const float* __restrict__ b2,
    float* __restrict__ out) {
  __shared__ float xs[4][1024];
  __shared__ float sig[4][64];
  __shared__ float smix[4][64];
  const int t = threadIdx.x;
  const int b0 = blockIdx.x * 4;
  const int wv = t >> 6, l64 = t & 63;
#pragma unroll
  for (int c = 0; c < 4; ++c) {
    int i = l64 * 4 + c * 256;
    *(float4*)&xs[wv][i] = *(const float4*)(x + (size_t)(b0 + wv) * 1024 + i);
  }
  __syncthreads();
  // fused x -> bf16 cast (this grid covers x exactly once: thread t owns
  // elements [wv][l64*16 .. +15])
  {
    int col0 = l64 * 16;
    u16x8 o0, o1;
#pragma unroll
    for (int j = 0; j < 8; ++j) o0[j] = f2b(xs[wv][col0 + j]);
#pragma unroll
    for (int j = 0; j < 8; ++j) o1[j] = f2b(xs[wv][col0 + 8 + j]);
    u16* p = g_Xb + (size_t)(b0 + wv) * 1024 + col0;
    *(u16x8*)p = o0;
    *(u16x8*)(p + 8) = o1;
  }
  // each wave handles nodes wv, wv+4, ...
  for (int n = wv; n < 63; n += 4) {
    float a0 = 0.f, a1 = 0.f, a2 = 0.f, a3 = 0.f;
#pragma unroll
    for (int c = 0; c < 4; ++c) {
      int i = l64 * 4 + c * 256;
      float4 w = *(const float4*)(nw + (size_t)n * 1024 + i);
      float4 x0 = *(const float4*)&xs[0][i];
      float4 x1 = *(const float4*)&xs[1][i];
      float4 x2 = *(const float4*)&xs[2][i];
      float4 x3 = *(const float4*)&xs[3][i];
      a0 += w.x * x0.x + w.y * x0.y + w.z * x0.z + w.w * x0.w;
      a1 += w.x * x1.x + w.y * x1.y + w.z * x1.z + w.w * x1.w;
      a2 += w.x * x2.x + w.y * x2.y + w.z * x2.z + w.w * x2.w;
      a3 += w.x * x3.x + w.y * x3.y + w.z * x3.z + w.w * x3.w;
    }
#pragma unroll
    for (int off = 32; off > 0; off >>= 1) {
      a0 += __shfl_down(a0, off);
      a1 += __shfl_down(a1, off);
      a2 += __shfl_down(a2, off);
      a3 += __shfl_down(a3, off);
    }
    if (l64 == 0) {
      float bias = nb[n];
      sig[0][n] = 1.f / (1.f + __expf(-(a0 + bias)));
      sig[1][n] = 1.f / (1.f + __expf(-(a1 + bias)));
      sig[2][n] = 1.f / (1.f + __expf(-(a2 + bias)));
      sig[3][n] = 1.f / (1.f + __expf(-(a3 + bias)));
    }
  }
  __syncthreads();
  {
    float p = 1.f;
#pragma unroll
    for (int d = 0; d < FDEPTH; ++d) {
      int node = (1 << d) - 1 + (l64 >> (FDEPTH - d));
      int bit = (l64 >> (FDEPTH - 1 - d)) & 1;
      float s = sig[wv][node];
      p *= bit ? s : (1.f - s);
    }
    smix[wv][l64] = p;
    g_mix[(size_t)(b0 + wv) * 64 + l64] = p;
  }
  __syncthreads();
#pragma unroll
  for (int c = 0; c < 2; ++c) {
    int o = t + c * 256;
    float acc0 = 0.f, acc1 = 0.f, acc2 = 0.f, acc3 = 0.f;
    for (int l = 0; l < 64; ++l) {
      float bv = b2[(size_t)l * 512 + o];
      acc0 += smix[0][l] * bv;
      acc1 += smix[1][l] * bv;
      acc2 += smix[2][l] * bv;
      acc3 += smix[3][l] * bv;
    }
    out[(size_t)(b0 + 0) * 512 + o] = acc0;
    out[(size_t)(b0 + 1) * 512 + o] = acc1;
    out[(size_t)(b0 + 2) * 512 + o] = acc2;
    out[(size_t)(b0 + 3) * 512 + o] = acc3;
  }
}

// ------------- MFMA GEMM (MODE 1: X@W1t -> H'; MODE 2: H'@W2t -> +=out) -------------
// 128x128 tile, BK=64, global_load_lds staging (16 B/lane), XOR-swizzled LDS
// chunk layout: slot (row, c8s) holds global 16B-chunk c8s ^ (row&7), which
// spreads fragment ds_read_b128 across all 8 bank groups (conflict-free) at
// zero cost -- the swizzle is applied to the per-lane *global* address.
template <int MODE>
__global__ __launch_bounds__(256) void gemm_kernel(const float* __restrict__ b1,
                                                   float* __restrict__ out) {
  constexpr int BM = 128, BN = 128, BK = 64;
  constexpr int K = (MODE == 1) ? 1024 : 4096;
  constexpr int LD = K;
  constexpr int LDC = (MODE == 1) ? NH : OUTF;
  constexpr int KSPLIT = (MODE == 1) ? 1 : 4;
  constexpr int TM = 4, TN = 4;

  __shared__ u16 lsA[BM * BK];
  __shared__ u16 lsB[BN * BK];

  const u16* __restrict__ A = (MODE == 1) ? g_Xb : g_Hb;
  const u16* __restrict__ Bm = (MODE == 1) ? g_W1t : g_W2t;

  const int t = threadIdx.x;
  const int wv = t >> 6, ln = t & 63;
  const int wm = wv >> 1, wn = wv & 1;
  const int quad = ln >> 4, m16 = ln & 15;
  const int am0 = blockIdx.y * BM;
  const int bn0 = blockIdx.x * BN;
  const int kbeg = blockIdx.z * (K / KSPLIT);
  const int kend = kbeg + K / KSPLIT;

  f32x4 acc[TM][TN] = {};

  for (int kc = kbeg; kc < kend; kc += BK) {
#pragma unroll
    for (int i = 0; i < 4; ++i) {
      int id = i * 256 + t;
      int row = id >> 3;
      int c8 = (id & 7) ^ (row & 7);
      async16(A + (size_t)(am0 + row) * LD + kc + c8 * 8, lsA + (i * 256 + wv * 64) * 8);
    }
#pragma unroll
    for (int i = 0; i < 4; ++i) {
      int id = i * 256 + t;
      int row = id >> 3;
      int c8 = (id & 7) ^ (row & 7);
      async16(Bm + (size_t)(bn0 + row) * LD + kc + c8 * 8, lsB + (i * 256 + wv * 64) * 8);
    }
    __syncthreads();
#pragma unroll
    for (int ks = 0; ks < 2; ++ks) {
      bf16x8 aF[TM], bF[TN];
#pragma unroll
      for (int tm = 0; tm < TM; ++tm) {
        int row = wm * 64 + tm * 16 + m16;
        aF[tm] = *(const bf16x8*)(lsA + row * BK + ((ks * 4 + quad) ^ (row & 7)) * 8);
      }
#pragma unroll
      for (int tn = 0; tn < TN; ++tn) {
        int row = wn * 64 + tn * 16 + m16;
        bF[tn] = *(const bf16x8*)(lsB + row * BK + ((ks * 4 + quad) ^ (row & 7)) * 8);
      }
#pragma unroll
      for (int tm = 0; tm < TM; ++tm)
#pragma unroll
        for (int tn = 0; tn < TN; ++tn)
          acc[tm][tn] = __builtin_amdgcn_mfma_f32_16x16x32_bf16(aF[tm], bF[tn], acc[tm][tn], 0, 0, 0);
    }
    __syncthreads();
  }

  if (MODE == 1) {
    float b1v[TN];
    int ls[TN];
#pragma unroll
    for (int tn = 0; tn < TN; ++tn) {
      int col = bn0 + wn * 64 + tn * 16 + m16;
      b1v[tn] = b1[col];
      ls[tn] = col >> 6;
    }
#pragma unroll
    for (int tm = 0; tm < TM; ++tm) {
#pragma unroll
      for (int r = 0; r < 4; ++r) {
        int row = am0 + wm * 64 + tm * 16 + quad * 4 + r;
        const float* mrow = g_mix + (size_t)row * 64;
#pragma unroll
        for (int tn = 0; tn < TN; ++tn) {
          int col = bn0 + wn * 64 + tn * 16 + m16;
          float v = acc[tm][tn][r] + b1v[tn];
          v = fmaxf(v, 0.f) * mrow[ls[tn]];
          g_Hb[(size_t)row * LDC + col] = f2b(v);
        }
      }
    }
  } else {
#pragma unroll
    for (int tm = 0; tm < TM; ++tm)
#pragma unroll
      for (int r = 0; r < 4; ++r) {
        int row = am0 + wm * 64 + tm * 16 + quad * 4 + r;
#pragma unroll
        for (int tn = 0; tn < TN; ++tn) {
          int col = bn0 + wn * 64 + tn * 16 + m16;
          atomicAdd(&out[(size_t)row * LDC + col], acc[tm][tn][r]);
        }
      }
  }
}

extern "C" void kernel_launch(void* const* d_in, const int* in_sizes, int n_in,
                              void* d_out, int out_size, void* d_ws, size_t ws_size,
                              hipStream_t stream) {
  const float* x = (const float*)d_in[0];
  const float* nw = (const float*)d_in[1];
  const float* nb = (const float*)d_in[2];
  const float* w1s = (const float*)d_in[3];
  const float* b1s = (const float*)d_in[4];
  const float* w2s = (const float*)d_in[5];
  const float* b2s = (const float*)d_in[6];
  float* out = (float*)d_out;
  (void)d_ws; (void)ws_size;

  hipLaunchKernelGGL(transpose_cast_kernel, dim3(1, 16, 64), dim3(256), 0, stream,
                     w1s, 0, 1024, 64);
  hipLaunchKernelGGL(transpose_cast_kernel, dim3(8, 64, 1), dim3(256), 0, stream,
                     w2s, 1, 4096, 512);
  hipLaunchKernelGGL(mixture_bias_kernel, dim3(1024), dim3(256), 0, stream,
                     x, nw, nb, b2s, out);
  hipLaunchKernelGGL(gemm_kernel<1>, dim3(32, 32, 1), dim3(256), 0, stream, b1s, out);
  hipLaunchKernelGGL(gemm_kernel<2>, dim3(4, 32, 4), dim3(256), 0, stream, b1s, out);
}

// Round 3
// 241.656 us; speedup vs baseline: 1.1506x; 1.0322x over previous
//
#include <hip/hip_runtime.h>
#include <hip/hip_bf16.h>

typedef unsigned short u16;
typedef __attribute__((ext_vector_type(8))) short bf16x8;
typedef __attribute__((ext_vector_type(4))) float f32x4;
typedef __attribute__((ext_vector_type(4))) unsigned short u16x4;
typedef __attribute__((ext_vector_type(8))) unsigned short u16x8;

#define BATCH 4096
#define INF   1024
#define NH    4096   // 64 leaves * 64 hidden
#define OUTF  512
#define NLEAF 64
#define FDEPTH 6

// Scratch as device globals (fully rewritten every call; no ws_size dependency).
__device__ __align__(16) u16  g_Xb[(size_t)BATCH * INF];    // x, bf16 (b,k)
__device__ __align__(16) u16  g_W1t[(size_t)NH * INF];      // W1 transposed: (n, k)
__device__ __align__(16) u16  g_W2t[(size_t)OUTF * NH];     // W2 transposed: (o, k)
__device__ __align__(16) u16  g_Hb[(size_t)BATCH * NH];     // H' = mix*relu(h), bf16 (b, n)
__device__ __align__(16) float g_mix[(size_t)BATCH * NLEAF];
__device__ __align__(16) float g_part[4 * (size_t)BATCH * OUTF];  // GEMM2 split-K partials

__device__ inline u16 f2b(float f) {
  __hip_bfloat16 h = __float2bfloat16(f);
  return *reinterpret_cast<u16*>(&h);
}

// Direct global->LDS DMA, 16 B per lane. lds ptr must be wave-uniform; lane i's
// data lands at lptr + i*16.
__device__ inline void async16(const u16* g, u16* l) {
  __builtin_amdgcn_global_load_lds((const __attribute__((address_space(1))) void*)g,
                                   (__attribute__((address_space(3))) void*)l, 16, 0, 0);
}

// ------------- batched transpose + cast: dst[b][c][r] = src[b][r][c] -------------
// which==0 -> g_W1t (batch=64, R=1024, C=64); which==1 -> g_W2t (batch=1, R=4096, C=512)
__global__ __launch_bounds__(256) void transpose_cast_kernel(const float* __restrict__ src,
                                                             int which, int R, int C) {
  __shared__ float tile[64 * 65];
  u16* dstbase = which ? g_W2t : g_W1t;
  const float* sb = src + (size_t)blockIdx.z * R * C;
  u16* db = dstbase + (size_t)blockIdx.z * R * C;
  int r0 = blockIdx.y * 64, c0 = blockIdx.x * 64;
  int t = threadIdx.x;
  int cc4 = (t & 15) * 4;
#pragma unroll
  for (int it = 0; it < 4; ++it) {
    int rr = (t >> 4) + it * 16;
    float4 v = *(const float4*)(sb + (size_t)(r0 + rr) * C + c0 + cc4);
    tile[rr * 65 + cc4 + 0] = v.x;
    tile[rr * 65 + cc4 + 1] = v.y;
    tile[rr * 65 + cc4 + 2] = v.z;
    tile[rr * 65 + cc4 + 3] = v.w;
  }
  __syncthreads();
  int cc = t >> 2, rch = (t & 3) * 16;
  u16x8 o0, o1;
#pragma unroll
  for (int j = 0; j < 8; ++j) o0[j] = f2b(tile[(rch + j) * 65 + cc]);
#pragma unroll
  for (int j = 0; j < 8; ++j) o1[j] = f2b(tile[(rch + 8 + j) * 65 + cc]);
  u16* p = db + (size_t)(c0 + cc) * R + r0 + rch;
  *(u16x8*)p = o0;
  *(u16x8*)(p + 8) = o1;
}

// ------------- mixture (fp32) + out := mix @ b2s + x -> bf16 cast -------------
__global__ __launch_bounds__(256) void mixture_bias_kernel(
    const float* __restrict__ x, const float* __restrict__ nw,
    const float* __restrict__ nb, const float* __restrict__ b2,
    float* __restrict__ out) {
  __shared__ float xs[4][1024];
  __shared__ float sig[4][64];
  __shared__ float smix[4][64];
  const int t = threadIdx.x;
  const int b0 = blockIdx.x * 4;
  const int wv = t >> 6, l64 = t & 63;
#pragma unroll
  for (int c = 0; c < 4; ++c) {
    int i = l64 * 4 + c * 256;
    *(float4*)&xs[wv][i] = *(const float4*)(x + (size_t)(b0 + wv) * 1024 + i);
  }
  __syncthreads();
  // fused x -> bf16 cast
  {
    int col0 = l64 * 16;
    u16x8 o0, o1;
#pragma unroll
    for (int j = 0; j < 8; ++j) o0[j] = f2b(xs[wv][col0 + j]);
#pragma unroll
    for (int j = 0; j < 8; ++j) o1[j] = f2b(xs[wv][col0 + 8 + j]);
    u16* p = g_Xb + (size_t)(b0 + wv) * 1024 + col0;
    *(u16x8*)p = o0;
    *(u16x8*)(p + 8) = o1;
  }
  for (int n = wv; n < 63; n += 4) {
    float a0 = 0.f, a1 = 0.f, a2 = 0.f, a3 = 0.f;
#pragma unroll
    for (int c = 0; c < 4; ++c) {
      int i = l64 * 4 + c * 256;
      float4 w = *(const float4*)(nw + (size_t)n * 1024 + i);
      float4 x0 = *(const float4*)&xs[0][i];
      float4 x1 = *(const float4*)&xs[1][i];
      float4 x2 = *(const float4*)&xs[2][i];
      float4 x3 = *(const float4*)&xs[3][i];
      a0 += w.x * x0.x + w.y * x0.y + w.z * x0.z + w.w * x0.w;
      a1 += w.x * x1.x + w.y * x1.y + w.z * x1.z + w.w * x1.w;
      a2 += w.x * x2.x + w.y * x2.y + w.z * x2.z + w.w * x2.w;
      a3 += w.x * x3.x + w.y * x3.y + w.z * x3.z + w.w * x3.w;
    }
#pragma unroll
    for (int off = 32; off > 0; off >>= 1) {
      a0 += __shfl_down(a0, off);
      a1 += __shfl_down(a1, off);
      a2 += __shfl_down(a2, off);
      a3 += __shfl_down(a3, off);
    }
    if (l64 == 0) {
      float bias = nb[n];
      sig[0][n] = 1.f / (1.f + __expf(-(a0 + bias)));
      sig[1][n] = 1.f / (1.f + __expf(-(a1 + bias)));
      sig[2][n] = 1.f / (1.f + __expf(-(a2 + bias)));
      sig[3][n] = 1.f / (1.f + __expf(-(a3 + bias)));
    }
  }
  __syncthreads();
  {
    float p = 1.f;
#pragma unroll
    for (int d = 0; d < FDEPTH; ++d) {
      int node = (1 << d) - 1 + (l64 >> (FDEPTH - d));
      int bit = (l64 >> (FDEPTH - 1 - d)) & 1;
      float s = sig[wv][node];
      p *= bit ? s : (1.f - s);
    }
    smix[wv][l64] = p;
    g_mix[(size_t)(b0 + wv) * 64 + l64] = p;
  }
  __syncthreads();
#pragma unroll
  for (int c = 0; c < 2; ++c) {
    int o = t + c * 256;
    float acc0 = 0.f, acc1 = 0.f, acc2 = 0.f, acc3 = 0.f;
    for (int l = 0; l < 64; ++l) {
      float bv = b2[(size_t)l * 512 + o];
      acc0 += smix[0][l] * bv;
      acc1 += smix[1][l] * bv;
      acc2 += smix[2][l] * bv;
      acc3 += smix[3][l] * bv;
    }
    out[(size_t)(b0 + 0) * 512 + o] = acc0;
    out[(size_t)(b0 + 1) * 512 + o] = acc1;
    out[(size_t)(b0 + 2) * 512 + o] = acc2;
    out[(size_t)(b0 + 3) * 512 + o] = acc3;
  }
}

// ------------- MFMA GEMM, role-swapped C layout -------------
// First (m-role) operand = WEIGHT fragment, second = DATA(batch) fragment.
// => C/D mapping (verified col=lane&15, row=quad*4+reg): each thread holds
// 4 CONSECUTIVE output-column values at a fixed batch row -> vectorizable
// epilogue stores.
// MODE 1: H'^(b,n) = mix * relu(Xb @ W1t^T + b1); LDS-repack -> dwordx4 rows.
// MODE 2: part[z](b,o) = Hb @ W2t^T (split-K partials, f32x4 direct stores).
template <int MODE>
__global__ __launch_bounds__(256) void gemm_kernel(const float* __restrict__ b1,
                                                   float* __restrict__ out) {
  constexpr int BM = 128, BN = 128, BK = 64;
  constexpr int K = (MODE == 1) ? 1024 : 4096;
  constexpr int LD = K;
  constexpr int KSPLIT = (MODE == 1) ? 1 : 4;
  constexpr int EPST = 72;  // epilogue repack stride (u16): 144 B, 16B-aligned
  constexpr int LDSU = (MODE == 1) ? (4 * 64 * EPST) : (BM * BK + BN * BK);

  __shared__ u16 lsmem[LDSU];
  u16* lsA = lsmem;            // batch rows (second operand)
  u16* lsB = lsmem + BM * BK;  // weight rows (first operand)

  const u16* __restrict__ A = (MODE == 1) ? g_Xb : g_Hb;
  const u16* __restrict__ Bm = (MODE == 1) ? g_W1t : g_W2t;

  const int t = threadIdx.x;
  const int wv = t >> 6, ln = t & 63;
  const int wm = wv >> 1, wn = wv & 1;   // wm: batch half, wn: col half
  const int quad = ln >> 4, m16 = ln & 15;
  const int am0 = blockIdx.y * BM;       // batch origin
  const int bn0 = blockIdx.x * BN;       // output-col origin
  const int kbeg = blockIdx.z * (K / KSPLIT);
  const int kend = kbeg + K / KSPLIT;

  f32x4 acc[4][4] = {};  // [tw: col tile][tb: batch tile]

  for (int kc = kbeg; kc < kend; kc += BK) {
#pragma unroll
    for (int i = 0; i < 4; ++i) {
      int id = i * 256 + t;
      int row = id >> 3;
      int c8 = (id & 7) ^ (row & 7);
      async16(A + (size_t)(am0 + row) * LD + kc + c8 * 8, lsA + (i * 256 + wv * 64) * 8);
    }
#pragma unroll
    for (int i = 0; i < 4; ++i) {
      int id = i * 256 + t;
      int row = id >> 3;
      int c8 = (id & 7) ^ (row & 7);
      async16(Bm + (size_t)(bn0 + row) * LD + kc + c8 * 8, lsB + (i * 256 + wv * 64) * 8);
    }
    __syncthreads();
#pragma unroll
    for (int ks = 0; ks < 2; ++ks) {
      bf16x8 wF[4], xF[4];
#pragma unroll
      for (int tw = 0; tw < 4; ++tw) {
        int row = wn * 64 + tw * 16 + m16;
        wF[tw] = *(const bf16x8*)(lsB + row * BK + ((ks * 4 + quad) ^ (row & 7)) * 8);
      }
#pragma unroll
      for (int tb = 0; tb < 4; ++tb) {
        int row = wm * 64 + tb * 16 + m16;
        xF[tb] = *(const bf16x8*)(lsA + row * BK + ((ks * 4 + quad) ^ (row & 7)) * 8);
      }
#pragma unroll
      for (int tw = 0; tw < 4; ++tw)
#pragma unroll
        for (int tb = 0; tb < 4; ++tb)
          acc[tw][tb] = __builtin_amdgcn_mfma_f32_16x16x32_bf16(wF[tw], xF[tb], acc[tw][tb], 0, 0, 0);
    }
    __syncthreads();
  }

  if (MODE == 1) {
    // Epilogue: v = relu(acc + b1[n]) * mix[b][leaf]; repack via LDS so global
    // stores are 128B-contiguous dwordx4 rows.
    const int leaf = (bn0 >> 6) + wn;  // col block spans one leaf per wave half
    u16* ep = lsmem + wv * (64 * EPST);
#pragma unroll
    for (int tw = 0; tw < 4; ++tw) {
      int n0g = bn0 + wn * 64 + tw * 16 + quad * 4;
      float4 b1v = *(const float4*)(b1 + n0g);
      int nl = tw * 16 + quad * 4;
#pragma unroll
      for (int tb = 0; tb < 4; ++tb) {
        int bg = am0 + wm * 64 + tb * 16 + m16;
        float mixv = g_mix[(size_t)bg * 64 + leaf];
        f32x4 a = acc[tw][tb];
        u16x4 pk;
        pk[0] = f2b(fmaxf(a[0] + b1v.x, 0.f) * mixv);
        pk[1] = f2b(fmaxf(a[1] + b1v.y, 0.f) * mixv);
        pk[2] = f2b(fmaxf(a[2] + b1v.z, 0.f) * mixv);
        pk[3] = f2b(fmaxf(a[3] + b1v.w, 0.f) * mixv);
        *(u16x4*)(ep + (tb * 16 + m16) * EPST + nl) = pk;
      }
    }
    __syncthreads();
    const u16* eprd = lsmem + wv * (64 * EPST);
    int rrow = ln >> 3, ch = ln & 7;
#pragma unroll
    for (int p = 0; p < 8; ++p) {
      int bl = p * 8 + rrow;
      uint4 v = *(const uint4*)(eprd + bl * EPST + ch * 8);
      *(uint4*)(g_Hb + (size_t)(am0 + wm * 64 + bl) * NH + bn0 + wn * 64 + ch * 8) = v;
    }
  } else {
    float* part = g_part + (size_t)blockIdx.z * ((size_t)BATCH * OUTF);
#pragma unroll
    for (int tw = 0; tw < 4; ++tw) {
      int og = bn0 + wn * 64 + tw * 16 + quad * 4;
#pragma unroll
      for (int tb = 0; tb < 4; ++tb) {
        int bg = am0 + wm * 64 + tb * 16 + m16;
        *(f32x4*)(part + (size_t)bg * OUTF + og) = acc[tw][tb];
      }
    }
  }
  (void)out;
}

// ------------- out += sum_z part[z] -------------
__global__ __launch_bounds__(256) void reduce_kernel(float* __restrict__ out) {
  int i = (blockIdx.x * 256 + threadIdx.x) * 4;
  float4 s = *(const float4*)(out + i);  // seed = mix @ b2s (from mixture kernel)
#pragma unroll
  for (int z = 0; z < 4; ++z) {
    const float4 p = *(const float4*)(g_part + (size_t)z * BATCH * OUTF + i);
    s.x += p.x; s.y += p.y; s.z += p.z; s.w += p.w;
  }
  *(float4*)(out + i) = s;
}

extern "C" void kernel_launch(void* const* d_in, const int* in_sizes, int n_in,
                              void* d_out, int out_size, void* d_ws, size_t ws_size,
                              hipStream_t stream) {
  const float* x = (const float*)d_in[0];
  const float* nw = (const float*)d_in[1];
  const float* nb = (const float*)d_in[2];
  const float* w1s = (const float*)d_in[3];
  const float* b1s = (const float*)d_in[4];
  const float* w2s = (const float*)d_in[5];
  const float* b2s = (const float*)d_in[6];
  float* out = (float*)d_out;
  (void)d_ws; (void)ws_size;

  hipLaunchKernelGGL(transpose_cast_kernel, dim3(1, 16, 64), dim3(256), 0, stream,
                     w1s, 0, 1024, 64);
  hipLaunchKernelGGL(transpose_cast_kernel, dim3(8, 64, 1), dim3(256), 0, stream,
                     w2s, 1, 4096, 512);
  hipLaunchKernelGGL(mixture_bias_kernel, dim3(1024), dim3(256), 0, stream,
                     x, nw, nb, b2s, out);
  hipLaunchKernelGGL(gemm_kernel<1>, dim3(32, 32, 1), dim3(256), 0, stream, b1s, out);
  hipLaunchKernelGGL(gemm_kernel<2>, dim3(4, 32, 4), dim3(256), 0, stream, b1s, out);
  hipLaunchKernelGGL(reduce_kernel, dim3(2048), dim3(256), 0, stream, out);
}